// Round 1
// baseline (1220.835 us; speedup 1.0000x reference)
//
#include <hip/hip_runtime.h>

// out[n,o] = sum_s attn[s] * (X[s] @ W[s])[n,o] + bias[o]
// == GEMM: A[N=200000][K=1024] (X fp32, k=(s,i)) x B[K][128] (attn-folded W, bf16)
//
// V2: LDS-free streaming GEMM.
//  - prep kernel folds attn into W -> bf16 Wt, tiled [kb][col][64k] (unchanged).
//  - main kernel: 128 rows/block, 32 rows/wave (each row owned by exactly ONE
//    wave -> no duplicate HBM traffic). A-fragments loaded global->VGPR as
//    2x f32x4 and converted to bf16 in-register; B-fragments loaded directly
//    from L2-resident Wt (256 KiB total). No LDS, no __syncthreads -> waves
//    never drain the HBM queue at a barrier; 24 outstanding loads/wave.
//  - 200000 % 32 == 0 -> tail block's waves are fully-valid or fully-OOB:
//    single wave-uniform early return, no per-row guards anywhere.
// Memory-bound floor ~146us (922 MB @ 6.3 TB/s).

typedef __bf16 bf16x8 __attribute__((ext_vector_type(8)));
typedef float  f32x4  __attribute__((ext_vector_type(4)));

#define N_DIM 200000

// Wt[((k>>6)*128 + o)*64 + (k&63)] = bf16(attn[k>>7] * W[k*128 + o]), k = s*128+i
__global__ void prep_w_kernel(const float* __restrict__ W,
                              const float* __restrict__ attn,
                              __bf16* __restrict__ Wt) {
    const int idx = blockIdx.x * 256 + threadIdx.x;   // 0..131071
    const int o = idx >> 10;                          // 0..127
    const int k = idx & 1023;                         // 0..1023
    const int s = k >> 7;
    const float v = attn[s] * W[(size_t)k * 128 + o];
    Wt[((size_t)(k >> 6) * 128 + o) * 64 + (k & 63)] = (__bf16)v;
}

__global__ __launch_bounds__(256, 2)
void mgc_kernel(const float* __restrict__ X,
                const __bf16* __restrict__ Wt,
                const float* __restrict__ bias,
                float* __restrict__ out) {
    const int tid  = threadIdx.x;
    const int lane = tid & 63;
    const int wave = tid >> 6;
    const int l15  = lane & 15;
    const int quad = lane >> 4;

    const long n0 = (long)blockIdx.x * 128;
    const long r0 = n0 + wave * 32;          // this wave's first row
    if (r0 >= N_DIM) return;                 // tail block: waves 2,3 fully OOB

    f32x4 acc[2][8] = {};                    // [row-tile i][col-tile j]

    #pragma unroll 1
    for (int kb = 0; kb < 16; ++kb) {
        const int s  = kb >> 1;
        const int i0 = (kb & 1) * 64;
        // A: X[s][r0 + i*16 + l15][i0 + kx*32 + quad*8 .. +8]
        const float*  Ab = X + ((size_t)s * N_DIM + (size_t)(r0 + l15)) * 128
                             + i0 + quad * 8;
        // B: Wt[kb*8192 + (j*16 + l15)*64 + kx*32 + quad*8 .. +8]
        const __bf16* Bb = Wt + (size_t)kb * 8192 + (size_t)l15 * 64 + quad * 8;

        // ---- issue ALL loads for this k-step (8x A-HBM + 16x B-L2, dwordx4) ----
        f32x4 a[2][2][2];                    // [i][kx][half], fp32
        #pragma unroll
        for (int i = 0; i < 2; ++i)
            #pragma unroll
            for (int kx = 0; kx < 2; ++kx) {
                const f32x4* p = (const f32x4*)(Ab + (size_t)(i * 16) * 128 + kx * 32);
                a[i][kx][0] = p[0];
                a[i][kx][1] = p[1];
            }

        bf16x8 bf[8][2];                     // [j][kx]
        #pragma unroll
        for (int j = 0; j < 8; ++j)
            #pragma unroll
            for (int kx = 0; kx < 2; ++kx)
                bf[j][kx] = *(const bf16x8*)(Bb + (size_t)j * 1024 + kx * 32);

        // ---- convert A fp32 -> bf16 in-register ----
        bf16x8 abf[2][2];
        #pragma unroll
        for (int i = 0; i < 2; ++i)
            #pragma unroll
            for (int kx = 0; kx < 2; ++kx) {
                const f32x4 v0 = a[i][kx][0], v1 = a[i][kx][1];
                bf16x8 w;
                w[0] = (__bf16)v0.x; w[1] = (__bf16)v0.y;
                w[2] = (__bf16)v0.z; w[3] = (__bf16)v0.w;
                w[4] = (__bf16)v1.x; w[5] = (__bf16)v1.y;
                w[6] = (__bf16)v1.z; w[7] = (__bf16)v1.w;
                abf[i][kx] = w;
            }

        // ---- 32 MFMA ----
        #pragma unroll
        for (int kx = 0; kx < 2; ++kx)
            #pragma unroll
            for (int i = 0; i < 2; ++i)
                #pragma unroll
                for (int j = 0; j < 8; ++j)
                    acc[i][j] = __builtin_amdgcn_mfma_f32_16x16x32_bf16(
                        abf[i][kx], bf[j][kx], acc[i][j], 0, 0, 0);
    }

    // ---- epilogue: bias add + store (C/D layout: col=lane&15, row=quad*4+reg) ----
    float bv[8];
    #pragma unroll
    for (int j = 0; j < 8; ++j)
        bv[j] = bias[j * 16 + l15];

    #pragma unroll
    for (int i = 0; i < 2; ++i) {
        #pragma unroll
        for (int reg = 0; reg < 4; ++reg) {
            const long r = r0 + i * 16 + quad * 4 + reg;   // always valid (wave-uniform)
            float* orow = out + r * 128 + l15;
            #pragma unroll
            for (int j = 0; j < 8; ++j)
                __builtin_nontemporal_store(acc[i][j][reg] + bv[j], &orow[j * 16]);
        }
    }
}

extern "C" void kernel_launch(void* const* d_in, const int* in_sizes, int n_in,
                              void* d_out, int out_size, void* d_ws, size_t ws_size,
                              hipStream_t stream) {
    const float* X    = (const float*)d_in[0];   // [8][200000][128]
    const float* W    = (const float*)d_in[1];   // [8][128][128]
    const float* attn = (const float*)d_in[2];   // [8]
    const float* bias = (const float*)d_in[3];   // [128]
    float* out = (float*)d_out;                  // [200000][128]
    __bf16* Wt = (__bf16*)d_ws;                  // 1024*128*2 = 256 KiB scratch

    prep_w_kernel<<<512, 256, 0, stream>>>(W, attn, Wt);
    const int nblocks = (N_DIM + 127) / 128;     // 1563 (last block: 64 valid rows)
    mgc_kernel<<<nblocks, 256, 0, stream>>>(X, Wt, bias, out);
}

// Round 4
// 1187.046 us; speedup vs baseline: 1.0285x; 1.0285x over previous
//
#include <hip/hip_runtime.h>

// out[n,o] = sum_s attn[s] * (X[s] @ W[s])[n,o] + bias[o]
// == GEMM: A[N=200000][K=1024] (X fp32, k=(s,i)) x B[K][128] (attn-folded W, bf16)
//
// V4: barrier-free per-wave pipeline.
//  - Each wave owns a disjoint 32x128 output tile (N_DIM % 32 == 0 -> waves
//    fully valid or fully OOB; OOB waves return immediately; NO barriers).
//  - A staged wave-privately: coalesced f32x4 loads -> cvt bf16 -> private LDS
//    region -> MFMA fragments. Same-wave ds ordering via compiler lgkmcnt.
//  - B fragments read directly from L2-resident Wt (256 KiB total).
//  - A register-prefetched 2 tiles deep (a0/a1, statically indexed); B issued
//    one phase ahead. Register deps => counted vmcnt waits; with no barriers a
//    wave never drains the HBM queue.
// Memory-bound floor ~146us (922 MB @ 6.3 TB/s) for the GEMM dispatch.

typedef __bf16 bf16x8 __attribute__((ext_vector_type(8)));
typedef float  f32x4  __attribute__((ext_vector_type(4)));

#define N_DIM 200000
#define LDSS  72   // LDS row stride in bf16 elems (64 + 8 pad)

// Wt[((k>>6)*128 + o)*64 + (k&63)] = bf16(attn[k>>7] * W[k*128 + o]), k = s*128+i
__global__ void prep_w_kernel(const float* __restrict__ W,
                              const float* __restrict__ attn,
                              __bf16* __restrict__ Wt) {
    const int idx = blockIdx.x * 256 + threadIdx.x;   // 0..131071
    const int o = idx >> 10;                          // 0..127
    const int k = idx & 1023;                         // 0..1023
    const int s = k >> 7;
    const float v = attn[s] * W[(size_t)k * 128 + o];
    Wt[((size_t)(k >> 6) * 128 + o) * 64 + (k & 63)] = (__bf16)v;
}

__global__ __launch_bounds__(256, 2)
void mgc_kernel(const float* __restrict__ X,
                const __bf16* __restrict__ Wt,
                const float* __restrict__ bias,
                float* __restrict__ out) {
    __shared__ __bf16 As[2][4][32 * LDSS];   // [buf][wave][row*LDSS+k], 36 KiB

    const int tid  = threadIdx.x;
    const int lane = tid & 63;
    const int wave = tid >> 6;
    const int l15  = lane & 15;
    const int quad = lane >> 4;
    const int arow = lane >> 3;        // staging row-within-pass (0..7)
    const int acol = (lane & 7) * 8;   // staging k offset (8 elems)

    const long n0 = (long)blockIdx.x * 128;
    const long r0 = n0 + (long)wave * 32;    // this wave's first row
    if (r0 >= N_DIM) return;                 // tail block: fully-OOB waves exit

    __bf16* myA0 = &As[0][wave][0];          // wave-private double buffer
    __bf16* myA1 = &As[1][wave][0];

    f32x4  acc[2][8] = {};                   // [row-tile i][col-tile j]
    f32x4  a0[8], a1[8];                     // A prefetch sets (static idx)
    bf16x8 bf[8][2];                         // B fragments [j][kx]

// issue 8 coalesced global loads for tile t's A-slice (32 rows x 64 k)
#define LOADA(t, ar) do {                                                      \
    const int s_  = (t) >> 1;                                                  \
    const int i0_ = ((t) & 1) * 64;                                            \
    const float* base_ = X + ((size_t)s_ * N_DIM + (size_t)(r0 + arow)) * 128  \
                           + i0_ + acol;                                       \
    _Pragma("unroll")                                                          \
    for (int p = 0; p < 4; ++p) {                                              \
        const f32x4* src_ = (const f32x4*)(base_ + (size_t)(p * 8) * 128);     \
        ar[2 * p]     = src_[0];                                               \
        ar[2 * p + 1] = src_[1];                                               \
    }                                                                          \
} while (0)

// consume a reg set (vmcnt waits exactly these), cvt fp32->bf16, ds_write
#define STAGEA(ar, dst) do {                                                   \
    _Pragma("unroll")                                                          \
    for (int p = 0; p < 4; ++p) {                                              \
        const f32x4 v0_ = ar[2 * p], v1_ = ar[2 * p + 1];                      \
        bf16x8 w_;                                                             \
        w_[0] = (__bf16)v0_.x; w_[1] = (__bf16)v0_.y;                          \
        w_[2] = (__bf16)v0_.z; w_[3] = (__bf16)v0_.w;                          \
        w_[4] = (__bf16)v1_.x; w_[5] = (__bf16)v1_.y;                          \
        w_[6] = (__bf16)v1_.z; w_[7] = (__bf16)v1_.w;                          \
        *(bf16x8*)(&dst[(p * 8 + arow) * LDSS + acol]) = w_;                   \
    }                                                                          \
} while (0)

// 16 b128 loads of B fragments for tile t (L2-resident, V2-verified layout)
#define LOADB(t) do {                                                          \
    const __bf16* Bb_ = Wt + (size_t)(t) * 8192 + (size_t)l15 * 64 + quad * 8; \
    _Pragma("unroll")                                                          \
    for (int j = 0; j < 8; ++j) {                                              \
        bf[j][0] = *(const bf16x8*)(Bb_ + (size_t)j * 1024);                   \
        bf[j][1] = *(const bf16x8*)(Bb_ + (size_t)j * 1024 + 32);              \
    }                                                                          \
} while (0)

// 4 ds_read_b128 + 32 MFMA from this wave's private LDS slice
#define COMP(srcA) do {                                                        \
    _Pragma("unroll")                                                          \
    for (int kx = 0; kx < 2; ++kx) {                                           \
        bf16x8 af_[2];                                                         \
        _Pragma("unroll")                                                      \
        for (int i = 0; i < 2; ++i)                                            \
            af_[i] = *(const bf16x8*)(&srcA[(i * 16 + l15) * LDSS              \
                                            + kx * 32 + quad * 8]);            \
        _Pragma("unroll")                                                      \
        for (int i = 0; i < 2; ++i)                                            \
            _Pragma("unroll")                                                  \
            for (int j = 0; j < 8; ++j)                                        \
                acc[i][j] = __builtin_amdgcn_mfma_f32_16x16x32_bf16(           \
                    af_[i], bf[j][kx], acc[i][j], 0, 0, 0);                    \
    }                                                                          \
} while (0)

    // ---- prologue: tiles 0,1 A in flight; B(0) in flight; stage tile 0 ----
    LOADA(0, a0);
    LOADB(0);
    LOADA(1, a1);
    STAGEA(a0, myA0);        // waits a0 only; B(0)+a1 stay outstanding

    // ---- steady state (no barriers anywhere) ----
    #pragma unroll 1
    for (int t = 0; t <= 12; t += 2) {
        LOADA(t + 2, a0);    // issue next-next A
        COMP(myA0);          // tile t   (bf = B(t))
        LOADB(t + 1);        // bf free after COMP -> refill
        STAGEA(a1, myA1);    // stage tile t+1 (waits a1; a0/B stay out)
        LOADA(t + 3, a1);
        COMP(myA1);          // tile t+1 (bf = B(t+1))
        LOADB(t + 2);
        STAGEA(a0, myA0);    // stage tile t+2
    }

    // ---- epilogue: tiles 14, 15 ----
    COMP(myA0);              // tile 14 (bf = B(14))
    LOADB(15);
    STAGEA(a1, myA1);        // tile 15
    COMP(myA1);              // tile 15

    // ---- bias add + store (C/D layout: col=lane&15, row=quad*4+reg) ----
    float bv[8];
    #pragma unroll
    for (int j = 0; j < 8; ++j)
        bv[j] = bias[j * 16 + l15];

    #pragma unroll
    for (int i = 0; i < 2; ++i) {
        #pragma unroll
        for (int reg = 0; reg < 4; ++reg) {
            const long r = r0 + i * 16 + quad * 4 + reg;   // always valid
            float* orow = out + r * 128 + l15;
            #pragma unroll
            for (int j = 0; j < 8; ++j)
                orow[j * 16] = acc[i][j][reg] + bv[j];
        }
    }

#undef LOADA
#undef STAGEA
#undef LOADB
#undef COMP
}

extern "C" void kernel_launch(void* const* d_in, const int* in_sizes, int n_in,
                              void* d_out, int out_size, void* d_ws, size_t ws_size,
                              hipStream_t stream) {
    const float* X    = (const float*)d_in[0];   // [8][200000][128]
    const float* W    = (const float*)d_in[1];   // [8][128][128]
    const float* attn = (const float*)d_in[2];   // [8]
    const float* bias = (const float*)d_in[3];   // [128]
    float* out = (float*)d_out;                  // [200000][128]
    __bf16* Wt = (__bf16*)d_ws;                  // 1024*128*2 = 256 KiB scratch

    prep_w_kernel<<<512, 256, 0, stream>>>(W, attn, Wt);
    const int nblocks = (N_DIM + 127) / 128;     // 1563 (last block: 64 valid rows)
    mgc_kernel<<<nblocks, 256, 0, stream>>>(X, Wt, bias, out);
}